// Round 7
// baseline (228.858 us; speedup 1.0000x reference)
//
#include <hip/hip_runtime.h>

// RelativeMultiHeadAttention on MI355X (gfx950)
// cast_all -> proj_qkv (128x128, 2-stage dbuf, counted vmcnt + raw barriers) ->
// rel_attn (flash, swapped-QK, no-max exp2 softmax, ones-MFMA row sums) ->
// proj_out (64x128, same discipline)
// ws layout (bytes):
//   [0,          8388608)  x_bf16   [16384][256] bf16   (reused as attn_out)
//   [8388608,    8912896)  Wcat     [1024][256]  bf16   rows: Wq|Wk|Wv|Wo
//   [8912896,   17301504)  q_buf    [128][1024][32] bf16 (scale*log2e folded)
//   [17301504,  25690112)  k_buf    [128][1024][32] bf16
//   [25690112,  34078720)  v_t      [128][32][1024] bf16

typedef unsigned short u16;
typedef unsigned int u32;
typedef short short8 __attribute__((ext_vector_type(8)));
typedef u16 u16x4 __attribute__((ext_vector_type(4)));
typedef u32 u32x2 __attribute__((ext_vector_type(2)));
typedef float f32x4 __attribute__((ext_vector_type(4)));

#define NREL 3969
#define LOG2E 1.4426950408889634f
#define QS2 (0.17677669529663687f * 1.4426950408889634f)

__device__ __forceinline__ u16 f2bf(float f) {
  union { float f; unsigned u; } x; x.f = f;
  unsigned r = x.u + 0x7fffu + ((x.u >> 16) & 1u);
  return (u16)(r >> 16);
}

__device__ __forceinline__ u32 cvt_pk_bf16(float lo, float hi) {
  u32 r;
  asm("v_cvt_pk_bf16_f32 %0, %1, %2" : "=v"(r) : "v"(lo), "v"(hi));
  return r;
}

__device__ __forceinline__ float fast_exp2(float x) {
  float r;
  asm("v_exp_f32 %0, %1" : "=v"(r) : "v"(x));
  return r;
}

__device__ __forceinline__ void glds16(const u16* g, u16* l) {
  __builtin_amdgcn_global_load_lds((const __attribute__((address_space(1))) u32*)g,
                                   (__attribute__((address_space(3))) u32*)l, 16, 0, 0);
}

template <int N> __device__ __forceinline__ void wait_vm() {
  asm volatile("s_waitcnt vmcnt(%0)" ::"n"(N) : "memory");
}

// x (1048576 float4) then Wq|Wk|Wv|Wo (65536 float4) -> bf16
__global__ __launch_bounds__(256) void cast_all_k(
    const float4* __restrict__ x,
    const float* __restrict__ wq, const float* __restrict__ wk,
    const float* __restrict__ wv, const float* __restrict__ wo,
    u16x4* __restrict__ xout, u16x4* __restrict__ wout) {
  int i = blockIdx.x * 256 + threadIdx.x;
  float4 v;
  u16x4* dst;
  if (i < 1048576) {
    v = x[i];
    dst = xout + i;
  } else {
    int wf = i - 1048576;
    int wi = wf >> 14, off = wf & 16383;
    const float* src = (wi == 0) ? wq : (wi == 1) ? wk : (wi == 2) ? wv : wo;
    v = ((const float4*)src)[off];
    dst = wout + wf;
  }
  u16x4 o;
  o[0] = f2bf(v.x); o[1] = f2bf(v.y); o[2] = f2bf(v.z); o[3] = f2bf(v.w);
  *dst = o;
}

// QKV projection: 128x128 tile, 4 waves (2x2 of 64x64), BK=32, 2-stage dbuf,
// attn-style discipline: prefetch-next -> counted wait_vm -> barrier -> compute
// -> barrier. XCD-chunked blockIdx, LDS-restaged (write-combining) epilogue.
__global__ __launch_bounds__(256, 4) void proj_qkv_k(
    const u16* __restrict__ A, const u16* __restrict__ Wc,
    const float* __restrict__ b0, const float* __restrict__ b1,
    const float* __restrict__ b2,
    u16* __restrict__ qb, u16* __restrict__ kb, u16* __restrict__ vtb) {
  const int lid = (blockIdx.x & 7) * 96 + (blockIdx.x >> 3);  // 768 = 8*96 bijective
  const int m0 = (lid / 6) * 128;
  const int n0 = (lid % 6) * 128;
  __shared__ u16 SH[16384];  // 32KB: 2 stages x [A 8KB][B 8KB]
  const int tid = threadIdx.x;
  const int wave = tid >> 6, lane = tid & 63;
  const int fr = lane & 15, kg = lane >> 4;
  const int wm = wave >> 1, wn = wave & 1;
  const int l2 = lane >> 2;
  const int sseg = ((lane & 3) ^ (l2 & 3)) * 8;   // pre-swizzled source col (u16)
  const u16* gA = A + (m0 + wave * 16 + l2) * 256 + sseg;
  const u16* gB = Wc + (n0 + wave * 16 + l2) * 256 + sseg;
  const int dstw = wave * 1024;  // byte offset within 4KB half-region
  const int rsw = (kg * 16) ^ ((fr & 3) << 4);

  f32x4 acc[4][4];
#pragma unroll
  for (int i = 0; i < 4; ++i)
#pragma unroll
    for (int j = 0; j < 4; ++j) acc[i][j] = (f32x4){0.f, 0.f, 0.f, 0.f};

  const int ws = (n0 + wn * 64) >> 8;  // 0=q 1=k 2=v, uniform per wave
  const bool vm = (ws == 2);

#define QSTG(t, sb)                                                         \
  do {                                                                      \
    glds16(gA + (t) * 32,         (u16*)((char*)SH + (sb) + dstw));         \
    glds16(gA + 16384 + (t) * 32, (u16*)((char*)SH + (sb) + 4096 + dstw));  \
    glds16(gB + (t) * 32,         (u16*)((char*)SH + (sb) + 8192 + dstw));  \
    glds16(gB + 16384 + (t) * 32, (u16*)((char*)SH + (sb) + 12288 + dstw)); \
  } while (0)

  QSTG(0, 0);
#pragma unroll 1
  for (int it = 0; it < 8; ++it) {
    const int cb = (it & 1) * 16384;  // current stage byte base
    const int nb = 16384 - cb;        // next stage
    if (it < 7) {
      QSTG(it + 1, nb);
      wait_vm<4>();  // current stage landed; next stays in flight
    } else {
      wait_vm<0>();
    }
    __builtin_amdgcn_s_barrier();
    const char* abase = (const char*)SH + cb;
    const char* bbase = abase + 8192;
    short8 af[4], bf[4];
#pragma unroll
    for (int i = 0; i < 4; ++i) {
      af[i] = *(const short8*)(abase + (wm * 64 + i * 16 + fr) * 64 + rsw);
      bf[i] = *(const short8*)(bbase + (wn * 64 + i * 16 + fr) * 64 + rsw);
    }
    if (vm) {
#pragma unroll
      for (int mi = 0; mi < 4; ++mi)
#pragma unroll
        for (int ni = 0; ni < 4; ++ni)
          acc[mi][ni] = __builtin_amdgcn_mfma_f32_16x16x32_bf16(af[mi], bf[ni], acc[mi][ni], 0, 0, 0);
    } else {
#pragma unroll
      for (int mi = 0; mi < 4; ++mi)
#pragma unroll
        for (int ni = 0; ni < 4; ++ni)
          acc[mi][ni] = __builtin_amdgcn_mfma_f32_16x16x32_bf16(bf[ni], af[mi], acc[mi][ni], 0, 0, 0);
    }
    __builtin_amdgcn_s_barrier();  // all reads of cb done before it's overwritten
  }
#undef QSTG

  const int bI = m0 >> 10;
  const int s0 = (m0 & 1023) + wm * 64;
  const int nbb = (n0 + wn * 64) & 255;
  char* shw = (char*)SH + wave * 8192;  // per-wave 8KB restage region
  if (vm) {
    // restage as [n_local 64][s 64] u16 (128B rows, XOR-swizzled)
#pragma unroll
    for (int ni = 0; ni < 4; ++ni) {
      const int nl = ni * 16 + fr;
      const float bias = b2[nbb + nl];
#pragma unroll
      for (int mi = 0; mi < 4; ++mi) {
        u16x4 pk;
#pragma unroll
        for (int r = 0; r < 4; ++r) pk[r] = f2bf(acc[mi][ni][r] + bias);
        *(u16x4*)(shw + nl * 128 + (((mi * 16 + kg * 4) * 2) ^ ((nl & 7) << 4))) = pk;
      }
    }
    const int l8 = lane >> 3, seg8 = lane & 7;
#pragma unroll
    for (int i = 0; i < 8; ++i) {
      const int nl = i * 8 + l8;
      const short8 val = *(const short8*)(shw + nl * 128 + ((seg8 * 16) ^ ((nl & 7) << 4)));
      const int hg = (nbb >> 5) + (nl >> 5), dd = nl & 31;
      *(short8*)(vtb + ((bI * 8 + hg) * 32 + dd) * 1024 + s0 + seg8 * 8) = val;
    }
  } else {
    // q/k (transposed acc): restage as [s_local 64][n 64] u16
    const float* bp = (ws == 0) ? b0 : b1;
    u16* dst = (ws == 0) ? qb : kb;
    const float sc = (ws == 0) ? QS2 : 1.0f;
#pragma unroll
    for (int ni = 0; ni < 4; ++ni) {
      const float4 b4 = *(const float4*)(bp + nbb + ni * 16 + kg * 4);
#pragma unroll
      for (int mi = 0; mi < 4; ++mi) {
        const int sl = mi * 16 + fr;
        u16x4 pk;
#pragma unroll
        for (int r = 0; r < 4; ++r) pk[r] = f2bf((acc[mi][ni][r] + b4[r]) * sc);
        *(u16x4*)(shw + sl * 128 + (((ni * 32 + kg * 8)) ^ ((sl & 7) << 4))) = pk;
      }
    }
    const int l4 = lane >> 2, seg = lane & 3;
#pragma unroll
    for (int hh = 0; hh < 2; ++hh) {
#pragma unroll
      for (int g = 0; g < 4; ++g) {
        const int sl = g * 16 + l4;
        const short8 val = *(const short8*)(shw + sl * 128 + ((hh * 64 + seg * 16) ^ ((sl & 7) << 4)));
        const int hg = (nbb >> 5) + hh;
        *(short8*)(dst + ((bI * 8 + hg) * 1024 + s0 + sl) * 32 + seg * 8) = val;
      }
    }
  }
}

// Output projection: 64x128 tile (4 waves of 32x64), 2-stage dbuf, same discipline.
__global__ __launch_bounds__(256, 4) void proj_out_k(
    const u16* __restrict__ A, const u16* __restrict__ Wc,
    const float* __restrict__ bo, float* __restrict__ outp) {
  const int lid = (blockIdx.x & 7) * 64 + (blockIdx.x >> 3);  // 512 = 8*64 bijective
  const int m0 = (lid >> 1) * 64;
  const int n0 = (lid & 1) * 128;
  __shared__ u16 SH[12288];  // 24KB = 2 stages x [A 4KB][B 8KB]
  const int tid = threadIdx.x;
  const int wave = tid >> 6, lane = tid & 63;
  const int fr = lane & 15, kg = lane >> 4;
  const int wm = wave >> 1, wn = wave & 1;
  const int l2 = lane >> 2;
  const int sseg = ((lane & 3) ^ (l2 & 3)) * 8;
  const u16* gA = A + (m0 + wave * 16 + l2) * 256 + sseg;
  const u16* gB = Wc + (768 + n0 + wave * 16 + l2) * 256 + sseg;
  const int dstw = wave * 1024;
  const int rsw = (kg * 16) ^ ((fr & 3) << 4);

  f32x4 acc[2][4];
#pragma unroll
  for (int i = 0; i < 2; ++i)
#pragma unroll
    for (int j = 0; j < 4; ++j) acc[i][j] = (f32x4){0.f, 0.f, 0.f, 0.f};

#define OSTG(t, sb)                                                        \
  do {                                                                     \
    glds16(gA + (t) * 32,         (u16*)((char*)SH + (sb) + dstw));        \
    glds16(gB + (t) * 32,         (u16*)((char*)SH + (sb) + 4096 + dstw)); \
    glds16(gB + 16384 + (t) * 32, (u16*)((char*)SH + (sb) + 8192 + dstw)); \
  } while (0)

  OSTG(0, 0);
#pragma unroll 1
  for (int it = 0; it < 8; ++it) {
    const int cb = (it & 1) * 12288;
    const int nb = 12288 - cb;
    if (it < 7) {
      OSTG(it + 1, nb);
      wait_vm<3>();
    } else {
      wait_vm<0>();
    }
    __builtin_amdgcn_s_barrier();
    const char* abase = (const char*)SH + cb;
    const char* bbase = abase + 4096;
    short8 af[2], bf[4];
#pragma unroll
    for (int i = 0; i < 2; ++i)
      af[i] = *(const short8*)(abase + (wm * 32 + i * 16 + fr) * 64 + rsw);
#pragma unroll
    for (int i = 0; i < 4; ++i)
      bf[i] = *(const short8*)(bbase + (wn * 64 + i * 16 + fr) * 64 + rsw);
#pragma unroll
    for (int mi = 0; mi < 2; ++mi)
#pragma unroll
      for (int ni = 0; ni < 4; ++ni)
        acc[mi][ni] = __builtin_amdgcn_mfma_f32_16x16x32_bf16(bf[ni], af[mi], acc[mi][ni], 0, 0, 0);
    __builtin_amdgcn_s_barrier();
  }
#undef OSTG

#pragma unroll
  for (int ni = 0; ni < 4; ++ni) {
    const int n4 = n0 + wn * 64 + ni * 16 + kg * 4;
    const float4 b4 = *(const float4*)(bo + n4);
#pragma unroll
    for (int mi = 0; mi < 2; ++mi) {
      const int m = m0 + wm * 32 + mi * 16 + fr;
      float4 o;
#pragma unroll
      for (int r = 0; r < 4; ++r) o[r] = acc[mi][ni][r] + b4[r];
      *(float4*)(outp + m * 256 + n4) = o;
    }
  }
}

// Flash attention, swapped QK^T. No online max (scores analytically bounded;
// softmax shift-invariant, exp2 range absorbs it). l via ones-MFMA (lane-aligned
// with O rows). bf16 bias table. Counted-vmcnt staging, 2 raw barriers/iter.
__global__ __launch_bounds__(256, 5) void rel_attn_k(
    const u16* __restrict__ qb, const u16* __restrict__ kb,
    const u16* __restrict__ vtb, const float* __restrict__ btab,
    u16* __restrict__ ao) {
  const int bid0 = blockIdx.x;
  const int lid = (bid0 & 7) * 256 + (bid0 >> 3);  // XCD chunking: same bh -> same XCD
  const int bh = lid >> 4, qt = lid & 15;
  const int h = bh & 7, b = bh >> 3;
  const int q0 = qt * 64;
  __shared__ u16 bias_lb[3972];  // bf16(btab*LOG2E), 7944B
  __shared__ u16 Kl[2][2048];    // [key 64][dk 32] rows 64B, src-preswizzled
  __shared__ u16 Vl[2][2048];    // [d 32][key 64] rows 128B, src-preswizzled
  __shared__ u16 Pl[4][1024];    // per-wave P tile [q 16][key 64], swizzled
  const int tid = threadIdx.x;
  const int wave = tid >> 6, lane = tid & 63;
  const int fr = lane & 15, kg = lane >> 4;

  for (int i = tid; i < NREL; i += 256) bias_lb[i] = f2bf(btab[h * NREL + i] * LOG2E);

  const int krow = tid >> 2;
  const u16* kgsrc = kb + (bh * 1024 + krow) * 32 + ((tid & 3) ^ (krow & 3)) * 8;
  const int vrow = tid >> 3;
  const u16* vgsrc = vtb + (bh * 32 + vrow) * 1024 + ((tid & 7) ^ (vrow & 7)) * 8;
  u16* kld = &Kl[0][0] + wave * 512;
  u16* vld = &Vl[0][0] + wave * 512;

  const int q = q0 + wave * 16 + fr;
  const short8 qf = *(const short8*)(qb + (bh * 1024 + q) * 32 + kg * 8);
  const int qbase = (q >> 5) * 63 + (q & 31) + 1984;
  char* pw = (char*)Pl[wave] + fr * 128;
  const int swz = (fr & 7) << 4;

  short8 ones;
#pragma unroll
  for (int j = 0; j < 8; ++j) ones[j] = (short)0x3F80;  // bf16 1.0

  f32x4 oacc[2], lacc;
  oacc[0] = (f32x4){0.f, 0.f, 0.f, 0.f};
  oacc[1] = (f32x4){0.f, 0.f, 0.f, 0.f};
  lacc = (f32x4){0.f, 0.f, 0.f, 0.f};

  glds16(kgsrc, kld);
  glds16(vgsrc, vld);
  __syncthreads();  // bias_lb ready + stage0 drained (only full drain in kernel)

  for (int kt = 0; kt < 16; ++kt) {
    const int cur = kt & 1;
    if (kt < 15) {
      glds16(kgsrc + (kt + 1) * 2048, kld + (cur ^ 1) * 2048);
      glds16(vgsrc + (kt + 1) * 64, vld + (cur ^ 1) * 2048);
      wait_vm<2>();  // stage kt landed; stage kt+1 stays in flight
    } else {
      wait_vm<0>();
    }
    __builtin_amdgcn_s_barrier();

    const char* kbase = (const char*)Kl[cur];
    const char* vbase = (const char*)Vl[cur];
    short8 kf[4], vf[2][2];
#pragma unroll
    for (int g = 0; g < 4; ++g)
      kf[g] = *(const short8*)(kbase + (g * 16 + fr) * 64 + ((kg * 16) ^ ((fr & 3) << 4)));
#pragma unroll
    for (int ks = 0; ks < 2; ++ks)
#pragma unroll
      for (int g2 = 0; g2 < 2; ++g2)
        vf[ks][g2] = *(const short8*)(vbase + (g2 * 16 + fr) * 128 + (((ks * 4 + kg) << 4) ^ swz));

    // S^T = K.Q (row=key, col=q=fr); scale*log2e folded into q
    f32x4 sacc[4];
    __builtin_amdgcn_s_setprio(1);
#pragma unroll
    for (int g = 0; g < 4; ++g)
      sacc[g] = __builtin_amdgcn_mfma_f32_16x16x32_bf16(kf[g], qf, (f32x4){0.f, 0.f, 0.f, 0.f}, 0, 0, 0);
    __builtin_amdgcn_s_setprio(0);

    // p = exp2(s + bias); bias idx = qbase - key - 31*ki (4 consecutive per g)
    const int t0 = qbase - kt * 126 - kg * 4;
    u32 pk[4][2];
#pragma unroll
    for (int g = 0; g < 4; ++g) {
      const int ag = t0 - g * 16 - 31 * (g >> 1);
      float e[4];
#pragma unroll
      for (int r = 0; r < 4; ++r) {
        union { u32 u; float f; } bc;
        bc.u = (u32)bias_lb[ag - r] << 16;
        e[r] = fast_exp2(sacc[g][r] + bc.f);
      }
      pk[g][0] = cvt_pk_bf16(e[0], e[1]);
      pk[g][1] = cvt_pk_bf16(e[2], e[3]);
    }

    // stage P (same-wave DS ops are ordered; no barrier needed)
#pragma unroll
    for (int g = 0; g < 4; ++g) {
      u32x2 w2;
      w2[0] = pk[g][0];
      w2[1] = pk[g][1];
      *(u32x2*)(pw + ((g * 32 + kg * 8) ^ swz)) = w2;
    }

    // O += P.V ; l += P.1 (row sums land lane-aligned with O rows)
#pragma unroll
    for (int ks = 0; ks < 2; ++ks) {
      const short8 pf = *(const short8*)(pw + ((ks * 64 + kg * 16) ^ swz));
      __builtin_amdgcn_s_setprio(1);
      oacc[0] = __builtin_amdgcn_mfma_f32_16x16x32_bf16(pf, vf[ks][0], oacc[0], 0, 0, 0);
      oacc[1] = __builtin_amdgcn_mfma_f32_16x16x32_bf16(pf, vf[ks][1], oacc[1], 0, 0, 0);
      lacc = __builtin_amdgcn_mfma_f32_16x16x32_bf16(pf, ones, lacc, 0, 0, 0);
      __builtin_amdgcn_s_setprio(0);
    }
    __builtin_amdgcn_s_barrier();  // all reads of buf[cur] done before next prefetch
  }

  // epilogue: divide by l (lane-aligned), restage O through Pl, coalesced stores
#pragma unroll
  for (int r = 0; r < 4; ++r) {
    const float inv = __builtin_amdgcn_rcpf(lacc[r]);
#pragma unroll
    for (int g2 = 0; g2 < 2; ++g2)
      *(u16*)((char*)Pl[wave] + (kg * 4 + r) * 64 + (g2 * 16 + fr) * 2) =
          f2bf(oacc[g2][r] * inv);
  }
  const int orow = lane >> 2, oseg = lane & 3;
  const short8 ov = *(const short8*)((char*)Pl[wave] + orow * 64 + oseg * 16);
  *(short8*)(ao + (b * 1024 + q0 + wave * 16 + orow) * 256 + h * 32 + oseg * 8) = ov;
}

extern "C" void kernel_launch(void* const* d_in, const int* in_sizes, int n_in,
                              void* d_out, int out_size, void* d_ws, size_t ws_size,
                              hipStream_t stream) {
  (void)in_sizes; (void)n_in; (void)out_size; (void)ws_size;
  const float* x    = (const float*)d_in[0];
  const float* Wq   = (const float*)d_in[1];
  const float* bq   = (const float*)d_in[2];
  const float* Wk   = (const float*)d_in[3];
  const float* bk   = (const float*)d_in[4];
  const float* Wv   = (const float*)d_in[5];
  const float* bv   = (const float*)d_in[6];
  const float* Wo   = (const float*)d_in[7];
  const float* bo   = (const float*)d_in[8];
  const float* btab = (const float*)d_in[9];
  // d_in[10] (rel_index) unused: recomputed analytically in-kernel.
  float* out = (float*)d_out;
  char* ws = (char*)d_ws;

  u16* xbf  = (u16*)(ws + 0);          // also attn_out after rel_attn_k
  u16* Wcat = (u16*)(ws + 8388608);
  u16* qbuf = (u16*)(ws + 8912896);
  u16* kbuf = (u16*)(ws + 17301504);
  u16* vtb  = (u16*)(ws + 25690112);

  cast_all_k<<<4352, 256, 0, stream>>>((const float4*)x, Wq, Wk, Wv, Wo,
                                       (u16x4*)xbf, (u16x4*)Wcat);
  proj_qkv_k<<<768, 256, 0, stream>>>(xbf, Wcat, bq, bk, bv, qbuf, kbuf, vtb);
  rel_attn_k<<<2048, 256, 0, stream>>>(qbuf, kbuf, vtb, btab, xbf);
  proj_out_k<<<512, 256, 0, stream>>>(xbf, Wcat, bo, out);
}

// Round 8
// 166.002 us; speedup vs baseline: 1.3786x; 1.3786x over previous
//
#include <hip/hip_runtime.h>

// RelativeMultiHeadAttention on MI355X (gfx950)
// cast_all -> proj_qkv (128x128, 3-stage counted-vmcnt pipeline, r5-exact) ->
// rel_attn (flash, swapped-QK, no-max exp2 softmax, ones-MFMA row sums,
//           2 q-tiles per block) -> proj_out (64x128, 3-stage, r5-exact)
// ws layout (bytes):
//   [0,          8388608)  x_bf16   [16384][256] bf16   (reused as attn_out)
//   [8388608,    8912896)  Wcat     [1024][256]  bf16   rows: Wq|Wk|Wv|Wo
//   [8912896,   17301504)  q_buf    [128][1024][32] bf16 (scale*log2e folded)
//   [17301504,  25690112)  k_buf    [128][1024][32] bf16
//   [25690112,  34078720)  v_t      [128][32][1024] bf16

typedef unsigned short u16;
typedef unsigned int u32;
typedef short short8 __attribute__((ext_vector_type(8)));
typedef u16 u16x4 __attribute__((ext_vector_type(4)));
typedef u32 u32x2 __attribute__((ext_vector_type(2)));
typedef float f32x4 __attribute__((ext_vector_type(4)));

#define NREL 3969
#define LOG2E 1.4426950408889634f
#define QS2 (0.17677669529663687f * 1.4426950408889634f)

__device__ __forceinline__ u16 f2bf(float f) {
  union { float f; unsigned u; } x; x.f = f;
  unsigned r = x.u + 0x7fffu + ((x.u >> 16) & 1u);
  return (u16)(r >> 16);
}

__device__ __forceinline__ u32 cvt_pk_bf16(float lo, float hi) {
  u32 r;
  asm("v_cvt_pk_bf16_f32 %0, %1, %2" : "=v"(r) : "v"(lo), "v"(hi));
  return r;
}

__device__ __forceinline__ float fast_exp2(float x) {
  float r;
  asm("v_exp_f32 %0, %1" : "=v"(r) : "v"(x));
  return r;
}

__device__ __forceinline__ void glds16(const u16* g, u16* l) {
  __builtin_amdgcn_global_load_lds((const __attribute__((address_space(1))) u32*)g,
                                   (__attribute__((address_space(3))) u32*)l, 16, 0, 0);
}

template <int N> __device__ __forceinline__ void wait_vm() {
  asm volatile("s_waitcnt vmcnt(%0)" ::"n"(N) : "memory");
}

// x (1048576 float4) then Wq|Wk|Wv|Wo (65536 float4) -> bf16
__global__ __launch_bounds__(256) void cast_all_k(
    const float4* __restrict__ x,
    const float* __restrict__ wq, const float* __restrict__ wk,
    const float* __restrict__ wv, const float* __restrict__ wo,
    u16x4* __restrict__ xout, u16x4* __restrict__ wout) {
  int i = blockIdx.x * 256 + threadIdx.x;
  float4 v;
  u16x4* dst;
  if (i < 1048576) {
    v = x[i];
    dst = xout + i;
  } else {
    int wf = i - 1048576;
    int wi = wf >> 14, off = wf & 16383;
    const float* src = (wi == 0) ? wq : (wi == 1) ? wk : (wi == 2) ? wv : wo;
    v = ((const float4*)src)[off];
    dst = wout + wf;
  }
  u16x4 o;
  o[0] = f2bf(v.x); o[1] = f2bf(v.y); o[2] = f2bf(v.z); o[3] = f2bf(v.w);
  *dst = o;
}

// QKV projection: 128x128 tile, 4 waves (2x2 of 64x64), BK=32, 3-stage pipeline,
// counted vmcnt (never drains to 0 in-loop), XCD-chunked blockIdx, LDS-restaged epilogue.
// (r5-exact structure: best measured proj variant this session.)
__global__ __launch_bounds__(256, 3) void proj_qkv_k(
    const u16* __restrict__ A, const u16* __restrict__ Wc,
    const float* __restrict__ b0, const float* __restrict__ b1,
    const float* __restrict__ b2,
    u16* __restrict__ qb, u16* __restrict__ kb, u16* __restrict__ vtb) {
  const int lid = (blockIdx.x & 7) * 96 + (blockIdx.x >> 3);  // 768 = 8*96 bijective
  const int m0 = (lid / 6) * 128;
  const int n0 = (lid % 6) * 128;
  __shared__ u16 SH[24576];  // 48KB = 3 stages x [A 8KB][B 8KB]
  const int tid = threadIdx.x;
  const int wave = tid >> 6, lane = tid & 63;
  const int fr = lane & 15, kg = lane >> 4;
  const int wm = wave >> 1, wn = wave & 1;
  const int l2 = lane >> 2;
  const int sseg = ((lane & 3) ^ (l2 & 3)) * 8;   // pre-swizzled source col (u16)
  const u16* gA = A + (m0 + wave * 16 + l2) * 256 + sseg;
  const u16* gB = Wc + (n0 + wave * 16 + l2) * 256 + sseg;
  const int dstw = wave * 1024;  // byte offset within 4KB half-region
  const int rsw = (kg * 16) ^ ((fr & 3) << 4);

  f32x4 acc[4][4];
#pragma unroll
  for (int i = 0; i < 4; ++i)
#pragma unroll
    for (int j = 0; j < 4; ++j) acc[i][j] = (f32x4){0.f, 0.f, 0.f, 0.f};

  const int ws = (n0 + wn * 64) >> 8;  // 0=q 1=k 2=v, uniform per wave
  const bool vm = (ws == 2);

#define PSTG(t, sb)                                                     \
  do {                                                                  \
    glds16(gA + (t) * 32,         (u16*)((char*)SH + (sb) + dstw));     \
    glds16(gA + 16384 + (t) * 32, (u16*)((char*)SH + (sb) + 4096 + dstw)); \
    glds16(gB + (t) * 32,         (u16*)((char*)SH + (sb) + 8192 + dstw)); \
    glds16(gB + 16384 + (t) * 32, (u16*)((char*)SH + (sb) + 12288 + dstw)); \
  } while (0)

  PSTG(0, 0);
  PSTG(1, 16384);
#pragma unroll
  for (int it = 0; it < 8; ++it) {
    if (it < 6) PSTG(it + 2, ((it + 2) % 3) * 16384);
    if (it < 6) wait_vm<8>();
    else if (it == 6) wait_vm<4>();
    else wait_vm<0>();
    __builtin_amdgcn_s_barrier();
    const char* abase = (const char*)SH + (it % 3) * 16384;
    const char* bbase = abase + 8192;
    short8 af[4], bf[4];
#pragma unroll
    for (int i = 0; i < 4; ++i) {
      af[i] = *(const short8*)(abase + (wm * 64 + i * 16 + fr) * 64 + rsw);
      bf[i] = *(const short8*)(bbase + (wn * 64 + i * 16 + fr) * 64 + rsw);
    }
    if (vm) {
#pragma unroll
      for (int mi = 0; mi < 4; ++mi)
#pragma unroll
        for (int ni = 0; ni < 4; ++ni)
          acc[mi][ni] = __builtin_amdgcn_mfma_f32_16x16x32_bf16(af[mi], bf[ni], acc[mi][ni], 0, 0, 0);
    } else {
#pragma unroll
      for (int mi = 0; mi < 4; ++mi)
#pragma unroll
        for (int ni = 0; ni < 4; ++ni)
          acc[mi][ni] = __builtin_amdgcn_mfma_f32_16x16x32_bf16(bf[ni], af[mi], acc[mi][ni], 0, 0, 0);
    }
    __builtin_amdgcn_s_barrier();
  }
#undef PSTG

  const int bI = m0 >> 10;
  const int s0 = (m0 & 1023) + wm * 64;
  const int nbb = (n0 + wn * 64) & 255;
  char* shw = (char*)SH + wave * 8192;  // per-wave 8KB restage region
  if (vm) {
    // restage as [n_local 64][s 64] u16 (128B rows, XOR-swizzled)
#pragma unroll
    for (int ni = 0; ni < 4; ++ni) {
      const int nl = ni * 16 + fr;
      const float bias = b2[nbb + nl];
#pragma unroll
      for (int mi = 0; mi < 4; ++mi) {
        u16x4 pk;
#pragma unroll
        for (int r = 0; r < 4; ++r) pk[r] = f2bf(acc[mi][ni][r] + bias);
        *(u16x4*)(shw + nl * 128 + (((mi * 16 + kg * 4) * 2) ^ ((nl & 7) << 4))) = pk;
      }
    }
    const int l8 = lane >> 3, seg8 = lane & 7;
#pragma unroll
    for (int i = 0; i < 8; ++i) {
      const int nl = i * 8 + l8;
      const short8 val = *(const short8*)(shw + nl * 128 + ((seg8 * 16) ^ ((nl & 7) << 4)));
      const int hg = (nbb >> 5) + (nl >> 5), dd = nl & 31;
      *(short8*)(vtb + ((bI * 8 + hg) * 32 + dd) * 1024 + s0 + seg8 * 8) = val;
    }
  } else {
    // q/k (transposed acc): restage as [s_local 64][n 64] u16
    const float* bp = (ws == 0) ? b0 : b1;
    u16* dst = (ws == 0) ? qb : kb;
    const float sc = (ws == 0) ? QS2 : 1.0f;
#pragma unroll
    for (int ni = 0; ni < 4; ++ni) {
      const float4 b4 = *(const float4*)(bp + nbb + ni * 16 + kg * 4);
#pragma unroll
      for (int mi = 0; mi < 4; ++mi) {
        const int sl = mi * 16 + fr;
        u16x4 pk;
#pragma unroll
        for (int r = 0; r < 4; ++r) pk[r] = f2bf((acc[mi][ni][r] + b4[r]) * sc);
        *(u16x4*)(shw + sl * 128 + (((ni * 32 + kg * 8)) ^ ((sl & 7) << 4))) = pk;
      }
    }
    const int l4 = lane >> 2, seg = lane & 3;
#pragma unroll
    for (int hh = 0; hh < 2; ++hh) {
#pragma unroll
      for (int g = 0; g < 4; ++g) {
        const int sl = g * 16 + l4;
        const short8 val = *(const short8*)(shw + sl * 128 + ((hh * 64 + seg * 16) ^ ((sl & 7) << 4)));
        const int hg = (nbb >> 5) + hh;
        *(short8*)(dst + ((bI * 8 + hg) * 1024 + s0 + sl) * 32 + seg * 8) = val;
      }
    }
  }
}

// Output projection: 64x128 tile (4 waves of 32x64), 3-stage pipeline, 512 blocks.
// (r5-exact structure.)
__global__ __launch_bounds__(256, 4) void proj_out_k(
    const u16* __restrict__ A, const u16* __restrict__ Wc,
    const float* __restrict__ bo, float* __restrict__ outp) {
  const int lid = (blockIdx.x & 7) * 64 + (blockIdx.x >> 3);  // 512 = 8*64 bijective
  const int m0 = (lid >> 1) * 64;
  const int n0 = (lid & 1) * 128;
  __shared__ u16 SH[18432];  // 36KB = 3 stages x [A 4KB][B 8KB]
  const int tid = threadIdx.x;
  const int wave = tid >> 6, lane = tid & 63;
  const int fr = lane & 15, kg = lane >> 4;
  const int wm = wave >> 1, wn = wave & 1;
  const int l2 = lane >> 2;
  const int sseg = ((lane & 3) ^ (l2 & 3)) * 8;
  const u16* gA = A + (m0 + wave * 16 + l2) * 256 + sseg;
  const u16* gB = Wc + (768 + n0 + wave * 16 + l2) * 256 + sseg;
  const int dstw = wave * 1024;
  const int rsw = (kg * 16) ^ ((fr & 3) << 4);

  f32x4 acc[2][4];
#pragma unroll
  for (int i = 0; i < 2; ++i)
#pragma unroll
    for (int j = 0; j < 4; ++j) acc[i][j] = (f32x4){0.f, 0.f, 0.f, 0.f};

#define OSTG(t, sb)                                                     \
  do {                                                                  \
    glds16(gA + (t) * 32,         (u16*)((char*)SH + (sb) + dstw));     \
    glds16(gB + (t) * 32,         (u16*)((char*)SH + (sb) + 4096 + dstw)); \
    glds16(gB + 16384 + (t) * 32, (u16*)((char*)SH + (sb) + 8192 + dstw)); \
  } while (0)

  OSTG(0, 0);
  OSTG(1, 12288);
#pragma unroll
  for (int it = 0; it < 8; ++it) {
    if (it < 6) OSTG(it + 2, ((it + 2) % 3) * 12288);
    if (it < 6) wait_vm<6>();
    else if (it == 6) wait_vm<3>();
    else wait_vm<0>();
    __builtin_amdgcn_s_barrier();
    const char* abase = (const char*)SH + (it % 3) * 12288;
    const char* bbase = abase + 4096;
    short8 af[2], bf[4];
#pragma unroll
    for (int i = 0; i < 2; ++i)
      af[i] = *(const short8*)(abase + (wm * 32 + i * 16 + fr) * 64 + rsw);
#pragma unroll
    for (int i = 0; i < 4; ++i)
      bf[i] = *(const short8*)(bbase + (wn * 64 + i * 16 + fr) * 64 + rsw);
#pragma unroll
    for (int mi = 0; mi < 2; ++mi)
#pragma unroll
      for (int ni = 0; ni < 4; ++ni)
        acc[mi][ni] = __builtin_amdgcn_mfma_f32_16x16x32_bf16(bf[ni], af[mi], acc[mi][ni], 0, 0, 0);
    __builtin_amdgcn_s_barrier();
  }
#undef OSTG

#pragma unroll
  for (int ni = 0; ni < 4; ++ni) {
    const int n4 = n0 + wn * 64 + ni * 16 + kg * 4;
    const float4 b4 = *(const float4*)(bo + n4);
#pragma unroll
    for (int mi = 0; mi < 2; ++mi) {
      const int m = m0 + wm * 32 + mi * 16 + fr;
      float4 o;
#pragma unroll
      for (int r = 0; r < 4; ++r) o[r] = acc[mi][ni][r] + b4[r];
      *(float4*)(outp + m * 256 + n4) = o;
    }
  }
}

// Flash attention, swapped QK^T, TWO q-tiles per block (staged K/V amortized 2x).
// No online max (scores analytically bounded; softmax shift-invariant). l via
// ones-MFMA. bf16 bias table. Counted-vmcnt staging, 2 raw barriers/iter.
// grid: 1024 blocks (XCD-chunked), 4 waves; wave owns q-rows [q0+w*16,+16) and +64.
__global__ __launch_bounds__(256, 5) void rel_attn_k(
    const u16* __restrict__ qb, const u16* __restrict__ kb,
    const u16* __restrict__ vtb, const float* __restrict__ btab,
    u16* __restrict__ ao) {
  const int bid0 = blockIdx.x;
  const int lid = (bid0 & 7) * 128 + (bid0 >> 3);  // 1024 = 8*128 bijective
  const int bh = lid >> 3, qp = lid & 7;
  const int h = bh & 7, b = bh >> 3;
  const int q0 = qp * 128;
  __shared__ u16 bias_lb[3972];  // bf16(btab*LOG2E), 7944B
  __shared__ u16 Kl[2][2048];    // [key 64][dk 32] rows 64B, src-preswizzled
  __shared__ u16 Vl[2][2048];    // [d 32][key 64] rows 128B, src-preswizzled
  __shared__ u16 Pl[4][1024];    // per-wave P tile [q 16][key 64], swizzled
  const int tid = threadIdx.x;
  const int wave = tid >> 6, lane = tid & 63;
  const int fr = lane & 15, kg = lane >> 4;

  for (int i = tid; i < NREL; i += 256) bias_lb[i] = f2bf(btab[h * NREL + i] * LOG2E);

  const int krow = tid >> 2;
  const u16* kgsrc = kb + (bh * 1024 + krow) * 32 + ((tid & 3) ^ (krow & 3)) * 8;
  const int vrow = tid >> 3;
  const u16* vgsrc = vtb + (bh * 32 + vrow) * 1024 + ((tid & 7) ^ (vrow & 7)) * 8;
  u16* kld = &Kl[0][0] + wave * 512;
  u16* vld = &Vl[0][0] + wave * 512;

  const int qA = q0 + wave * 16 + fr;          // tile A q-row
  const short8 qfA = *(const short8*)(qb + (bh * 1024 + qA) * 32 + kg * 8);
  const short8 qfB = *(const short8*)(qb + (bh * 1024 + qA + 64) * 32 + kg * 8);
  const int qbaseA = (qA >> 5) * 63 + (qA & 31) + 1984;
  const int qbaseB = qbaseA + 126;             // qB = qA + 64 -> qi+2
  char* pw = (char*)Pl[wave] + fr * 128;
  const int swz = (fr & 7) << 4;

  short8 ones;
#pragma unroll
  for (int j = 0; j < 8; ++j) ones[j] = (short)0x3F80;  // bf16 1.0

  f32x4 oaccA[2], oaccB[2], laccA, laccB;
  oaccA[0] = (f32x4){0.f, 0.f, 0.f, 0.f};
  oaccA[1] = (f32x4){0.f, 0.f, 0.f, 0.f};
  oaccB[0] = (f32x4){0.f, 0.f, 0.f, 0.f};
  oaccB[1] = (f32x4){0.f, 0.f, 0.f, 0.f};
  laccA = (f32x4){0.f, 0.f, 0.f, 0.f};
  laccB = (f32x4){0.f, 0.f, 0.f, 0.f};

  glds16(kgsrc, kld);
  glds16(vgsrc, vld);
  __syncthreads();  // bias_lb ready + stage0 drained (only full drain in kernel)

  for (int kt = 0; kt < 16; ++kt) {
    const int cur = kt & 1;
    if (kt < 15) {
      glds16(kgsrc + (kt + 1) * 2048, kld + (cur ^ 1) * 2048);
      glds16(vgsrc + (kt + 1) * 64, vld + (cur ^ 1) * 2048);
      wait_vm<2>();  // stage kt landed; stage kt+1 stays in flight
    } else {
      wait_vm<0>();
    }
    __builtin_amdgcn_s_barrier();

    const char* kbase = (const char*)Kl[cur];
    const char* vbase = (const char*)Vl[cur];
    short8 kf[4], vf[2][2];
#pragma unroll
    for (int g = 0; g < 4; ++g)
      kf[g] = *(const short8*)(kbase + (g * 16 + fr) * 64 + ((kg * 16) ^ ((fr & 3) << 4)));
#pragma unroll
    for (int ks = 0; ks < 2; ++ks)
#pragma unroll
      for (int g2 = 0; g2 < 2; ++g2)
        vf[ks][g2] = *(const short8*)(vbase + (g2 * 16 + fr) * 128 + (((ks * 4 + kg) << 4) ^ swz));

    const int t0k = -kt * 126 - kg * 4;

    // ---- tile A ----
    {
      f32x4 sacc[4];
      __builtin_amdgcn_s_setprio(1);
#pragma unroll
      for (int g = 0; g < 4; ++g)
        sacc[g] = __builtin_amdgcn_mfma_f32_16x16x32_bf16(kf[g], qfA, (f32x4){0.f, 0.f, 0.f, 0.f}, 0, 0, 0);
      __builtin_amdgcn_s_setprio(0);
      const int t0 = qbaseA + t0k;
      u32 pk[4][2];
#pragma unroll
      for (int g = 0; g < 4; ++g) {
        const int ag = t0 - g * 16 - 31 * (g >> 1);
        float e[4];
#pragma unroll
        for (int r = 0; r < 4; ++r) {
          union { u32 u; float f; } bc;
          bc.u = (u32)bias_lb[ag - r] << 16;
          e[r] = fast_exp2(sacc[g][r] + bc.f);
        }
        pk[g][0] = cvt_pk_bf16(e[0], e[1]);
        pk[g][1] = cvt_pk_bf16(e[2], e[3]);
      }
#pragma unroll
      for (int g = 0; g < 4; ++g) {
        u32x2 w2;
        w2[0] = pk[g][0];
        w2[1] = pk[g][1];
        *(u32x2*)(pw + ((g * 32 + kg * 8) ^ swz)) = w2;
      }
#pragma unroll
      for (int ks = 0; ks < 2; ++ks) {
        const short8 pf = *(const short8*)(pw + ((ks * 64 + kg * 16) ^ swz));
        __builtin_amdgcn_s_setprio(1);
        oaccA[0] = __builtin_amdgcn_mfma_f32_16x16x32_bf16(pf, vf[ks][0], oaccA[0], 0, 0, 0);
        oaccA[1] = __builtin_amdgcn_mfma_f32_16x16x32_bf16(pf, vf[ks][1], oaccA[1], 0, 0, 0);
        laccA = __builtin_amdgcn_mfma_f32_16x16x32_bf16(pf, ones, laccA, 0, 0, 0);
        __builtin_amdgcn_s_setprio(0);
      }
    }

    // ---- tile B (reuses Pl; same-wave DS ops are in-order) ----
    {
      f32x4 sacc[4];
      __builtin_amdgcn_s_setprio(1);
#pragma unroll
      for (int g = 0; g < 4; ++g)
        sacc[g] = __builtin_amdgcn_mfma_f32_16x16x32_bf16(kf[g], qfB, (f32x4){0.f, 0.f, 0.f, 0.f}, 0, 0, 0);
      __builtin_amdgcn_s_setprio(0);
      const int t0 = qbaseB + t0k;
      u32 pk[4][2];
#pragma unroll
      for (int g = 0; g < 4; ++g) {
        const int ag = t0 - g * 16 - 31 * (g >> 1);
        float e[4];
#pragma unroll
        for (int r = 0; r < 4; ++r) {
          union { u32 u; float f; } bc;
          bc.u = (u32)bias_lb[ag - r] << 16;
          e[r] = fast_exp2(sacc[g][r] + bc.f);
        }
        pk[g][0] = cvt_pk_bf16(e[0], e[1]);
        pk[g][1] = cvt_pk_bf16(e[2], e[3]);
      }
#pragma unroll
      for (int g = 0; g < 4; ++g) {
        u32x2 w2;
        w2[0] = pk[g][0];
        w2[1] = pk[g][1];
        *(u32x2*)(pw + ((g * 32 + kg * 8) ^ swz)) = w2;
      }
#pragma unroll
      for (int ks = 0; ks < 2; ++ks) {
        const short8 pf = *(const short8*)(pw + ((ks * 64 + kg * 16) ^ swz));
        __builtin_amdgcn_s_setprio(1);
        oaccB[0] = __builtin_amdgcn_mfma_f32_16x16x32_bf16(pf, vf[ks][0], oaccB[0], 0, 0, 0);
        oaccB[1] = __builtin_amdgcn_mfma_f32_16x16x32_bf16(pf, vf[ks][1], oaccB[1], 0, 0, 0);
        laccB = __builtin_amdgcn_mfma_f32_16x16x32_bf16(pf, ones, laccB, 0, 0, 0);
        __builtin_amdgcn_s_setprio(0);
      }
    }
    __builtin_amdgcn_s_barrier();  // all reads of buf[cur] done before next prefetch
  }

  // epilogue: divide by l (lane-aligned), restage O through Pl, coalesced stores.
  const int orow = lane >> 2, oseg = lane & 3;
#pragma unroll
  for (int r = 0; r < 4; ++r) {
    const float inv = __builtin_amdgcn_rcpf(laccA[r]);
#pragma unroll
    for (int g2 = 0; g2 < 2; ++g2)
      *(u16*)((char*)Pl[wave] + (kg * 4 + r) * 64 + (g2 * 16 + fr) * 2) =
          f2bf(oaccA[g2][r] * inv);
  }
  {
    const short8 ov = *(const short8*)((char*)Pl[wave] + orow * 64 + oseg * 16);
    *(short8*)(ao + (b * 1024 + q0 + wave * 16 + orow) * 256 + h * 32 + oseg * 8) = ov;
  }
#pragma unroll
  for (int r = 0; r < 4; ++r) {
    const float inv = __builtin_amdgcn_rcpf(laccB[r]);
#pragma unroll
    for (int g2 = 0; g2 < 2; ++g2)
      *(u16*)((char*)Pl[wave] + (kg * 4 + r) * 64 + (g2 * 16 + fr) * 2) =
          f2bf(oaccB[g2][r] * inv);
  }
  {
    const short8 ov = *(const short8*)((char*)Pl[wave] + orow * 64 + oseg * 16);
    *(short8*)(ao + (b * 1024 + q0 + 64 + wave * 16 + orow) * 256 + h * 32 + oseg * 8) = ov;
  }
}

extern "C" void kernel_launch(void* const* d_in, const int* in_sizes, int n_in,
                              void* d_out, int out_size, void* d_ws, size_t ws_size,
                              hipStream_t stream) {
  (void)in_sizes; (void)n_in; (void)out_size; (void)ws_size;
  const float* x    = (const float*)d_in[0];
  const float* Wq   = (const float*)d_in[1];
  const float* bq   = (const float*)d_in[2];
  const float* Wk   = (const float*)d_in[3];
  const float* bk   = (const float*)d_in[4];
  const float* Wv   = (const float*)d_in[5];
  const float* bv   = (const float*)d_in[6];
  const float* Wo   = (const float*)d_in[7];
  const float* bo   = (const float*)d_in[8];
  const float* btab = (const float*)d_in[9];
  // d_in[10] (rel_index) unused: recomputed analytically in-kernel.
  float* out = (float*)d_out;
  char* ws = (char*)d_ws;

  u16* xbf  = (u16*)(ws + 0);          // also attn_out after rel_attn_k
  u16* Wcat = (u16*)(ws + 8388608);
  u16* qbuf = (u16*)(ws + 8912896);
  u16* kbuf = (u16*)(ws + 17301504);
  u16* vtb  = (u16*)(ws + 25690112);

  cast_all_k<<<4352, 256, 0, stream>>>((const float4*)x, Wq, Wk, Wv, Wo,
                                       (u16x4*)xbf, (u16x4*)Wcat);
  proj_qkv_k<<<768, 256, 0, stream>>>(xbf, Wcat, bq, bk, bv, qbuf, kbuf, vtb);
  rel_attn_k<<<1024, 256, 0, stream>>>(qbuf, kbuf, vtb, btab, xbf);
  proj_out_k<<<512, 256, 0, stream>>>(xbf, Wcat, bo, out);
}